// Round 19
// baseline (152.965 us; speedup 1.0000x reference)
//
#include <hip/hip_runtime.h>

#define BLK 256
#define PSH 11
#define PART 2048          // nodes per dst-bucket
#define GHB 1024           // blocks in partition pass
#define MAXB 128           // max buckets (primary path requires NB <= 128)
#define BATCH 2048         // edges per write-combining batch
#define DKB 16             // degree / layer-2 slices per bucket
#define S1SCALE 2097152.0f // 2^21 fixed-point scale for layer-1 messages
#define S2SCALE 524288.0f  // 2^19 fixed-point scale for layer-2 messages

// ---------------- helpers ----------------

__device__ __forceinline__ int edge_at(const void* idx, int is64, long long pos) {
  return is64 ? (int)((const long long*)idx)[pos] : ((const int*)idx)[pos];
}

// Detect int64 vs int32 storage: for int64 values < 2^31 the odd 32-bit words are 0.
__global__ void k_detect(const unsigned* __restrict__ w, int* __restrict__ flag) {
  __shared__ int any;
  if (threadIdx.x == 0) any = 0;
  __syncthreads();
  if (w[2 * threadIdx.x + 1] != 0u) atomicOr(&any, 1);
  __syncthreads();
  if (threadIdx.x == 0) *flag = (any == 0) ? 1 : 0;  // 1 => int64
}

__global__ void k_zero_i(int* __restrict__ p, int n) {
  int i = blockIdx.x * blockDim.x + threadIdx.x;
  if (i < n) p[i] = 0;
}

// ---------------- fused hist+partition (single HBM edge read) ----------------
// Each block: (1) LDS histogram of its chunk, (2) ONE atomicAdd per bucket to
// reserve a contiguous sub-region in bucket b's region [b*cap, b*cap+cap),
// (3) re-read chunk (cache-warm) and emit via LDS write-combining.
// Regions fill contiguously (tight reservations), so bucket b's edges are
// packed[b*cap .. b*cap+bcursor[b]). Intra-bucket order is nondeterministic,
// but all consumers are exact int sums -> deterministic output.
__global__ __launch_bounds__(BLK) void k_fpart(const void* __restrict__ ei,
                                               const int* __restrict__ flag,
                                               int E, int chunk, int NB, int cap,
                                               int* __restrict__ bcursor,
                                               int* __restrict__ packed) {
  __shared__ int gcur[MAXB];
  __shared__ int bcnt[MAXB];
  __shared__ int bbase[MAXB];
  __shared__ int sc[MAXB];
  __shared__ int stage[BATCH];
  __shared__ unsigned char stgb[BATCH];
  const int t = threadIdx.x;
  int is64 = *flag;
  int beg = blockIdx.x * chunk, end = min(E, beg + chunk);
  const int U = BATCH / BLK;  // 8 edges per thread per batch

  // ---- pass 1: per-block bucket histogram (reuse sc[] as counter array) ----
  for (int j = t; j < NB; j += BLK) sc[j] = 0;
  __syncthreads();
  {
    int i = beg + t;
    for (; i + 3 * BLK < end; i += 4 * BLK) {
      int d0 = edge_at(ei, is64, (long long)E + i);
      int d1 = edge_at(ei, is64, (long long)E + i + BLK);
      int d2 = edge_at(ei, is64, (long long)E + i + 2 * BLK);
      int d3 = edge_at(ei, is64, (long long)E + i + 3 * BLK);
      atomicAdd(&sc[d0 >> PSH], 1);
      atomicAdd(&sc[d1 >> PSH], 1);
      atomicAdd(&sc[d2 >> PSH], 1);
      atomicAdd(&sc[d3 >> PSH], 1);
    }
    for (; i < end; i += BLK)
      atomicAdd(&sc[edge_at(ei, is64, (long long)E + i) >> PSH], 1);
  }
  __syncthreads();
  // ---- reserve: one global atomic per non-empty bucket ----
  if (t < NB) {
    int c = sc[t];
    gcur[t] = (c > 0) ? atomicAdd(&bcursor[t], c) : 0;
  }
  __syncthreads();

  // ---- pass 2: batch-staged write-combining partition (cache-warm reads) ----
  int myb[U], myv[U];
  {
    int bend0 = min(end, beg + BATCH);
#pragma unroll
    for (int u = 0; u < U; ++u) {
      int i = beg + u * BLK + t;
      myb[u] = -1;
      if (i < bend0) {
        int s = edge_at(ei, is64, i);
        int d = edge_at(ei, is64, (long long)E + i);
        myb[u] = d >> PSH;
        myv[u] = (s << PSH) | (d & (PART - 1));
      }
    }
  }

  for (int bb = beg; bb < end; bb += BATCH) {
    int bend = min(end, bb + BATCH);
    int len = bend - bb;
    for (int j = t; j < NB; j += BLK) bcnt[j] = 0;
    __syncthreads();
    int myr[U];
#pragma unroll
    for (int u = 0; u < U; ++u)
      if (myb[u] >= 0) myr[u] = atomicAdd(&bcnt[myb[u]], 1);
    __syncthreads();
    // inclusive scan of bcnt over MAXB lanes -> sc; exclusive base -> bbase
    if (t < MAXB) sc[t] = (t < NB) ? bcnt[t] : 0;
    __syncthreads();
    for (int off = 1; off < MAXB; off <<= 1) {
      int v = (t < MAXB && t >= off) ? sc[t - off] : 0;
      __syncthreads();
      if (t < MAXB) sc[t] += v;
      __syncthreads();
    }
    if (t < NB) bbase[t] = sc[t] - bcnt[t];
    __syncthreads();
    // scatter into bucket-sorted LDS stage
#pragma unroll
    for (int u = 0; u < U; ++u) {
      if (myb[u] >= 0) {
        int p = bbase[myb[u]] + myr[u];
        stage[p] = myv[u];
        stgb[p] = (unsigned char)myb[u];
      }
    }
    // prefetch next batch (overlaps copy + cursor phases)
    int nxb[U], nxv[U];
    int nb_ = bb + BATCH;
    if (nb_ < end) {
      int nbend = min(end, nb_ + BATCH);
#pragma unroll
      for (int u = 0; u < U; ++u) {
        int i = nb_ + u * BLK + t;
        nxb[u] = -1;
        nxv[u] = 0;
        if (i < nbend) {
          int s = edge_at(ei, is64, i);
          int d = edge_at(ei, is64, (long long)E + i);
          nxb[u] = d >> PSH;
          nxv[u] = (s << PSH) | (d & (PART - 1));
        }
      }
    } else {
#pragma unroll
      for (int u = 0; u < U; ++u) { nxb[u] = -1; nxv[u] = 0; }
    }
    __syncthreads();
    // coalesced copy: consecutive j within a bucket -> consecutive global addrs
    for (int j = t; j < len; j += BLK) {
      int b = stgb[j];
      int pos = gcur[b] + (j - bbase[b]);
      if (pos < cap) packed[(size_t)b * cap + pos] = stage[j];
    }
    __syncthreads();
    for (int j = t; j < NB; j += BLK) gcur[j] += bcnt[j];
#pragma unroll
    for (int u = 0; u < U; ++u) { myb[u] = nxb[u]; myv[u] = nxv[u]; }
    __syncthreads();
  }
}

// slice [lo,hi) of bucket b's region [b*cap, b*cap+len); head/vector/tail split
#define SLICE_BOUNDS(KB_)                                                     \
  int b = blockIdx.x, k = blockIdx.y;                                         \
  int s0 = b * cap;                                                           \
  int len = min(bcount[b], cap);                                              \
  int lo = s0 + (int)((long long)len * k / (KB_));                            \
  int hi = s0 + (int)((long long)len * (k + 1) / (KB_));                      \
  int alo = min((lo + 3) & ~3, hi);                                           \
  int nvec = (hi - alo) & ~3;                                                 \
  int tails = alo + nvec;

// degree count per bucket slice -> int partials [DKB][N]
__global__ __launch_bounds__(BLK) void k_degb(const int* __restrict__ packed,
                                              const int* __restrict__ bcount,
                                              int cap, int N, int* __restrict__ degp) {
  __shared__ int cnt[PART];
  for (int j = threadIdx.x; j < PART; j += BLK) cnt[j] = 0;
  __syncthreads();
  SLICE_BOUNDS(DKB)
  int t = threadIdx.x;
  if (t < alo - lo) atomicAdd(&cnt[packed[lo + t] & (PART - 1)], 1);
  for (int base = alo + t * 4; base < tails; base += BLK * 4) {
    int4 q = *(const int4*)(packed + base);
    atomicAdd(&cnt[q.x & (PART - 1)], 1);
    atomicAdd(&cnt[q.y & (PART - 1)], 1);
    atomicAdd(&cnt[q.z & (PART - 1)], 1);
    atomicAdd(&cnt[q.w & (PART - 1)], 1);
  }
  if (t < hi - tails) atomicAdd(&cnt[packed[tails + t] & (PART - 1)], 1);
  __syncthreads();
  int pstart = b << PSH;
  int psize = min(N - pstart, PART);
  int* out = degp + (size_t)k * N + pstart;
  for (int j = threadIdx.x; j < psize; j += BLK) out[j] = cnt[j];
}

// reduce degree partials -> gx4i = (round(dinv*x*S1), dinv_bits)
__global__ __launch_bounds__(BLK) void k_prepb(const int* __restrict__ degp,
                                               int N, const float* __restrict__ x,
                                               int4* __restrict__ gx4i) {
  int n = blockIdx.x * blockDim.x + threadIdx.x;
  if (n >= N) return;
  int deg = 1;  // self-loop
#pragma unroll
  for (int k = 0; k < DKB; ++k) deg += degp[(size_t)k * N + n];
  float di = rsqrtf((float)deg);
  int4 g;
  g.x = __float2int_rn(di * x[3 * n + 0] * S1SCALE);
  g.y = __float2int_rn(di * x[3 * n + 1] * S1SCALE);
  g.z = __float2int_rn(di * x[3 * n + 2] * S1SCALE);
  g.w = __float_as_int(di);
  gx4i[n] = g;
}

// layer-1 aggregation in LDS (native int atomics) -> int partials [S1KB][3N]
__global__ __launch_bounds__(BLK) void k_s1b(const int* __restrict__ packed,
                                             const int* __restrict__ bcount,
                                             int cap, int N, int S1KB,
                                             const int4* __restrict__ gx4i,
                                             int* __restrict__ p1) {
  __shared__ int acc[3 * PART];  // 24 KB
  for (int j = threadIdx.x; j < 3 * PART; j += BLK) acc[j] = 0;
  __syncthreads();
  SLICE_BOUNDS(S1KB)
  int t = threadIdx.x;
  if (t < alo - lo) {
    int e = packed[lo + t];
    int4 g = gx4i[e >> PSH];
    int a = 3 * (e & (PART - 1));
    atomicAdd(&acc[a + 0], g.x);
    atomicAdd(&acc[a + 1], g.y);
    atomicAdd(&acc[a + 2], g.z);
  }
  for (int base = alo + t * 4; base < tails; base += BLK * 4) {
    int4 q = *(const int4*)(packed + base);
    int4 g0 = gx4i[q.x >> PSH];
    int4 g1 = gx4i[q.y >> PSH];
    int4 g2 = gx4i[q.z >> PSH];
    int4 g3 = gx4i[q.w >> PSH];
    int a0 = 3 * (q.x & (PART - 1)), a1 = 3 * (q.y & (PART - 1));
    int a2 = 3 * (q.z & (PART - 1)), a3 = 3 * (q.w & (PART - 1));
    atomicAdd(&acc[a0 + 0], g0.x);
    atomicAdd(&acc[a0 + 1], g0.y);
    atomicAdd(&acc[a0 + 2], g0.z);
    atomicAdd(&acc[a1 + 0], g1.x);
    atomicAdd(&acc[a1 + 1], g1.y);
    atomicAdd(&acc[a1 + 2], g1.z);
    atomicAdd(&acc[a2 + 0], g2.x);
    atomicAdd(&acc[a2 + 1], g2.y);
    atomicAdd(&acc[a2 + 2], g2.z);
    atomicAdd(&acc[a3 + 0], g3.x);
    atomicAdd(&acc[a3 + 1], g3.y);
    atomicAdd(&acc[a3 + 2], g3.z);
  }
  if (t < hi - tails) {
    int e = packed[tails + t];
    int4 g = gx4i[e >> PSH];
    int a = 3 * (e & (PART - 1));
    atomicAdd(&acc[a + 0], g.x);
    atomicAdd(&acc[a + 1], g.y);
    atomicAdd(&acc[a + 2], g.z);
  }
  __syncthreads();
  int pstart = b << PSH;
  int psize = min(N - pstart, PART);
  int* out = p1 + (size_t)k * 3 * N + 3 * pstart;
  for (int j = threadIdx.x; j < 3 * psize; j += BLK) out[j] = acc[j];
}

// reduce layer-1 int partials + self-loop (exact int sum), fused W1+b1+relu+W2 -> g2i
__global__ __launch_bounds__(BLK) void k_midb(const int* __restrict__ p1, int S1KB,
                                              int N, const int4* __restrict__ gx4i,
                                              const float* __restrict__ W1,
                                              const float* __restrict__ b1,
                                              const float* __restrict__ W2,
                                              int* __restrict__ g2i) {
  int n = blockIdx.x * blockDim.x + threadIdx.x;
  if (n >= N) return;
  int4 g = gx4i[n];
  int A0 = g.x, A1 = g.y, A2 = g.z;  // self-loop (scaled)
  for (int k = 0; k < S1KB; ++k) {
    const int* pp = p1 + (size_t)k * 3 * N + 3 * n;
    A0 += pp[0]; A1 += pp[1]; A2 += pp[2];
  }
  float di = __int_as_float(g.w);
  float sc = di * (1.0f / S1SCALE);
  float a0 = (float)A0 * sc, a1 = (float)A1 * sc, a2 = (float)A2 * sc;
  float h2 = 0.0f;
#pragma unroll
  for (int k = 0; k < 16; ++k) {
    float o = fmaf(a0, W1[k], fmaf(a1, W1[16 + k], fmaf(a2, W1[32 + k], b1[k])));
    o = fmaxf(o, 0.0f);
    h2 = fmaf(o, W2[k], h2);
  }
  g2i[n] = __float2int_rn(di * h2 * S2SCALE);
}

// layer-2 aggregation in LDS (native int atomics) -> int partials [DKB][N]
__global__ __launch_bounds__(BLK) void k_s2b(const int* __restrict__ packed,
                                             const int* __restrict__ bcount,
                                             int cap, int N,
                                             const int* __restrict__ g2i,
                                             int* __restrict__ p2) {
  __shared__ int acc[PART];  // 8 KB
  for (int j = threadIdx.x; j < PART; j += BLK) acc[j] = 0;
  __syncthreads();
  SLICE_BOUNDS(DKB)
  int t = threadIdx.x;
  if (t < alo - lo) {
    int e = packed[lo + t];
    atomicAdd(&acc[e & (PART - 1)], g2i[e >> PSH]);
  }
  for (int base = alo + t * 4; base < tails; base += BLK * 4) {
    int4 q = *(const int4*)(packed + base);
    int v0 = g2i[q.x >> PSH], v1 = g2i[q.y >> PSH];
    int v2 = g2i[q.z >> PSH], v3 = g2i[q.w >> PSH];
    atomicAdd(&acc[q.x & (PART - 1)], v0);
    atomicAdd(&acc[q.y & (PART - 1)], v1);
    atomicAdd(&acc[q.z & (PART - 1)], v2);
    atomicAdd(&acc[q.w & (PART - 1)], v3);
  }
  if (t < hi - tails) {
    int e = packed[tails + t];
    atomicAdd(&acc[e & (PART - 1)], g2i[e >> PSH]);
  }
  __syncthreads();
  int pstart = b << PSH;
  int psize = min(N - pstart, PART);
  int* out = p2 + (size_t)k * N + pstart;
  for (int j = threadIdx.x; j < psize; j += BLK) out[j] = acc[j];
}

// reduce layer-2 int partials + self-loop + bias -> out
__global__ __launch_bounds__(BLK) void k_finalb(const int* __restrict__ p2,
                                                int N, const int* __restrict__ g2i,
                                                const int4* __restrict__ gx4i,
                                                const float* __restrict__ b2,
                                                float* __restrict__ out) {
  int n = blockIdx.x * blockDim.x + threadIdx.x;
  if (n >= N) return;
  int S = g2i[n];  // self-loop (scaled)
#pragma unroll
  for (int k = 0; k < DKB; ++k) S += p2[(size_t)k * N + n];
  float di = __int_as_float(gx4i[n].w);
  out[n] = di * ((float)S * (1.0f / S2SCALE)) + b2[0];
}

// ---------------- fallback (round-1 atomic) path ----------------

__global__ void k_zero(float* __restrict__ p, int n) {
  int i = blockIdx.x * blockDim.x + threadIdx.x;
  if (i < n) p[i] = 0.0f;
}

__global__ void k_deg(const void* __restrict__ idx, const int* __restrict__ flag,
                      int E, int* __restrict__ deg) {
  int i = blockIdx.x * blockDim.x + threadIdx.x;
  if (i >= E) return;
  int is64 = *flag;
  atomicAdd(&deg[edge_at(idx, is64, (long long)E + i)], 1);
}

__global__ void k_prep(const float* __restrict__ x, const int* __restrict__ deg,
                       float* __restrict__ dinv, float* __restrict__ gx, int N) {
  int n = blockIdx.x * blockDim.x + threadIdx.x;
  if (n >= N) return;
  float di = rsqrtf((float)(deg[n] + 1));
  dinv[n] = di;
  gx[3 * n + 0] = di * x[3 * n + 0];
  gx[3 * n + 1] = di * x[3 * n + 1];
  gx[3 * n + 2] = di * x[3 * n + 2];
}

__global__ void k_scat1(const void* __restrict__ idx, const int* __restrict__ flag,
                        int E, const float* __restrict__ gx, float* __restrict__ aggx) {
  int i = blockIdx.x * blockDim.x + threadIdx.x;
  if (i >= E) return;
  int is64 = *flag;
  int s = edge_at(idx, is64, i);
  int d = edge_at(idx, is64, (long long)E + i);
  unsafeAtomicAdd(&aggx[3 * d + 0], gx[3 * s + 0]);
  unsafeAtomicAdd(&aggx[3 * d + 1], gx[3 * s + 1]);
  unsafeAtomicAdd(&aggx[3 * d + 2], gx[3 * s + 2]);
}

__global__ void k_mid(const float* __restrict__ aggx, const float* __restrict__ gx,
                      const float* __restrict__ dinv,
                      const float* __restrict__ W1, const float* __restrict__ b1,
                      const float* __restrict__ W2, float* __restrict__ g2, int N) {
  int n = blockIdx.x * blockDim.x + threadIdx.x;
  if (n >= N) return;
  float di = dinv[n];
  float a0 = (aggx[3 * n + 0] + gx[3 * n + 0]) * di;
  float a1 = (aggx[3 * n + 1] + gx[3 * n + 1]) * di;
  float a2 = (aggx[3 * n + 2] + gx[3 * n + 2]) * di;
  float h2 = 0.0f;
#pragma unroll
  for (int k = 0; k < 16; ++k) {
    float o = fmaf(a0, W1[k], fmaf(a1, W1[16 + k], fmaf(a2, W1[32 + k], b1[k])));
    o = fmaxf(o, 0.0f);
    h2 = fmaf(o, W2[k], h2);
  }
  g2[n] = di * h2;
}

__global__ void k_scat2(const void* __restrict__ idx, const int* __restrict__ flag,
                        int E, const float* __restrict__ g2, float* __restrict__ agg2) {
  int i = blockIdx.x * blockDim.x + threadIdx.x;
  if (i >= E) return;
  int is64 = *flag;
  int s = edge_at(idx, is64, i);
  int d = edge_at(idx, is64, (long long)E + i);
  unsafeAtomicAdd(&agg2[d], g2[s]);
}

__global__ void k_final(const float* __restrict__ agg2, const float* __restrict__ g2,
                        const float* __restrict__ dinv, const float* __restrict__ b2,
                        float* __restrict__ out, int N) {
  int n = blockIdx.x * blockDim.x + threadIdx.x;
  if (n >= N) return;
  out[n] = dinv[n] * (agg2[n] + g2[n]) + b2[0];
}

// ---------------- launch ----------------

extern "C" void kernel_launch(void* const* d_in, const int* in_sizes, int n_in,
                              void* d_out, int out_size, void* d_ws, size_t ws_size,
                              hipStream_t stream) {
  const float* x  = (const float*)d_in[0];
  const void*  ei = d_in[1];
  const float* W1 = (const float*)d_in[2];
  const float* b1 = (const float*)d_in[3];
  const float* W2 = (const float*)d_in[4];
  const float* b2 = (const float*)d_in[5];
  float* out = (float*)d_out;

  const int N = in_sizes[0] / 3;   // 200000
  const int E = in_sizes[1] / 2;   // 6400000
  const int NB = (N + PART - 1) >> PSH;  // 98

  char* ws = (char*)d_ws;
  int gN = (N + BLK - 1) / BLK;
  int gE = (E + BLK - 1) / BLK;

  // bucket capacity: mean + 20% margin (≈38 binomial sigmas), rounded to 4
  int cap = (E + NB - 1) / NB;
  cap = (cap + cap / 5 + 3) & ~3;

  // ws layout (256B-aligned cursor)
  size_t cur = 0;
  auto take = [&](size_t bytes) { size_t o = cur; cur += (bytes + 255) & ~(size_t)255; return (void*)(ws + o); };
  int*   flag    = (int*)take(256);
  int*   bcursor = (int*)take((size_t)MAXB * 4);
  int*   packed  = (int*)take((size_t)NB * cap * 4);
  int4*  gx4i    = (int4*)take((size_t)N * 16);
  int*   g2i     = (int*)take((size_t)N * 4);
  size_t fixed = cur;

  // choose S1KB so partial region fits: partial = S1KB * 3N ints (>= DKB*N needed)
  int s1kb = 12;
  while (s1kb > 6 && fixed + (size_t)s1kb * 3 * N * 4 > ws_size) s1kb -= 2;

  if (fixed + (size_t)s1kb * 3 * N * 4 <= ws_size && NB <= MAXB) {
    int* partial = (int*)take((size_t)s1kb * 3 * N * 4);
    int chunk = (((E + GHB - 1) / GHB) + 3) & ~3;

    k_detect<<<1, 256, 0, stream>>>((const unsigned*)ei, flag);
    k_zero_i<<<1, MAXB, 0, stream>>>(bcursor, MAXB);
    k_fpart<<<GHB, BLK, 0, stream>>>(ei, flag, E, chunk, NB, cap, bcursor, packed);
    k_degb<<<dim3(NB, DKB), BLK, 0, stream>>>(packed, bcursor, cap, N, partial);
    k_prepb<<<gN, BLK, 0, stream>>>((const int*)partial, N, x, gx4i);
    k_s1b<<<dim3(NB, s1kb), BLK, 0, stream>>>(packed, bcursor, cap, N, s1kb, (const int4*)gx4i, partial);
    k_midb<<<gN, BLK, 0, stream>>>(partial, s1kb, N, (const int4*)gx4i, W1, b1, W2, g2i);
    k_s2b<<<dim3(NB, DKB), BLK, 0, stream>>>(packed, bcursor, cap, N, (const int*)g2i, partial);
    k_finalb<<<gN, BLK, 0, stream>>>(partial, N, (const int*)g2i, (const int4*)gx4i, b2, out);
  } else {
    // round-1 fallback
    int*   deg   = (int*)(ws + 256);
    float* aggx  = (float*)(ws + 256 + 4ll * N);
    float* agg2b = (float*)(ws + 256 + 4ll * N * 4);
    float* dinvf = (float*)(ws + 256 + 4ll * N * 5);
    float* gx    = (float*)(ws + 256 + 4ll * N * 6);
    float* g2f   = (float*)(ws + 256 + 4ll * N * 9);

    int gZ = (5 * N + BLK - 1) / BLK;

    k_detect<<<1, 256, 0, stream>>>((const unsigned*)ei, (int*)ws);
    k_zero<<<gZ, BLK, 0, stream>>>((float*)deg, 5 * N);
    k_deg<<<gE, BLK, 0, stream>>>(ei, (int*)ws, E, deg);
    k_prep<<<gN, BLK, 0, stream>>>(x, deg, dinvf, gx, N);
    k_scat1<<<gE, BLK, 0, stream>>>(ei, (int*)ws, E, gx, aggx);
    k_mid<<<gN, BLK, 0, stream>>>(aggx, gx, dinvf, W1, b1, W2, g2f, N);
    k_scat2<<<gE, BLK, 0, stream>>>(ei, (int*)ws, E, g2f, agg2b);
    k_final<<<gN, BLK, 0, stream>>>(agg2b, g2f, dinvf, b2, out, N);
  }
}

// Round 20
// 139.383 us; speedup vs baseline: 1.0974x; 1.0974x over previous
//
#include <hip/hip_runtime.h>

#define BLK 256
#define PSH 11
#define PART 2048          // nodes per dst-bucket
#define GHB 2048           // blocks in hist/partition passes
#define MAXB 256           // max buckets supported by LDS counters
#define BATCH 2048         // edges per write-combining batch in k_part_wc
#define DKB 16             // degree / layer-2 slices per bucket
#define S1SCALE 2097152.0f // 2^21 fixed-point scale for layer-1 messages
#define S2SCALE 524288.0f  // 2^19 fixed-point scale for layer-2 messages

// ---------------- helpers ----------------

__device__ __forceinline__ int edge_at(const void* idx, int is64, long long pos) {
  return is64 ? (int)((const long long*)idx)[pos] : ((const int*)idx)[pos];
}

// Detect int64 vs int32 storage: for int64 values < 2^31 the odd 32-bit words are 0.
__global__ void k_detect(const unsigned* __restrict__ w, int* __restrict__ flag) {
  __shared__ int any;
  if (threadIdx.x == 0) any = 0;
  __syncthreads();
  if (w[2 * threadIdx.x + 1] != 0u) atomicOr(&any, 1);
  __syncthreads();
  if (threadIdx.x == 0) *flag = (any == 0) ? 1 : 0;  // 1 => int64
}

// ---------------- bucketed (counting-sort) path ----------------

// per-block histogram of dst buckets; hist layout [block][bucket] (coalesced)
__global__ __launch_bounds__(BLK) void k_hist(const void* __restrict__ ei,
                                              const int* __restrict__ flag,
                                              int E, int chunk, int NB,
                                              int* __restrict__ hist) {
  __shared__ int cnt[MAXB];
  for (int j = threadIdx.x; j < NB; j += BLK) cnt[j] = 0;
  __syncthreads();
  int is64 = *flag;
  int beg = blockIdx.x * chunk, end = min(E, beg + chunk);
  int i = beg + (int)threadIdx.x;
  for (; i + 3 * BLK < end; i += 4 * BLK) {
    int d0 = edge_at(ei, is64, (long long)E + i);
    int d1 = edge_at(ei, is64, (long long)E + i + BLK);
    int d2 = edge_at(ei, is64, (long long)E + i + 2 * BLK);
    int d3 = edge_at(ei, is64, (long long)E + i + 3 * BLK);
    atomicAdd(&cnt[d0 >> PSH], 1);
    atomicAdd(&cnt[d1 >> PSH], 1);
    atomicAdd(&cnt[d2 >> PSH], 1);
    atomicAdd(&cnt[d3 >> PSH], 1);
  }
  for (; i < end; i += BLK)
    atomicAdd(&cnt[edge_at(ei, is64, (long long)E + i) >> PSH], 1);
  __syncthreads();
  int* row = hist + (size_t)blockIdx.x * NB;
  for (int j = threadIdx.x; j < NB; j += BLK) row[j] = cnt[j];
}

// per-bucket parallel scan over the GHB chunk counts; exclusive in place.
__global__ __launch_bounds__(BLK) void k_scan1(int* __restrict__ hist, int NB,
                                               int* __restrict__ btot) {
  const int R = GHB / BLK;
  __shared__ int sd[BLK];
  int b = blockIdx.x, t = threadIdx.x;
  int v[R];
  int sum = 0;
#pragma unroll
  for (int r = 0; r < R; ++r) {
    v[r] = hist[(size_t)(t * R + r) * NB + b];
    sum += v[r];
  }
  sd[t] = sum;
  __syncthreads();
  for (int off = 1; off < BLK; off <<= 1) {
    int tmp = (t >= off) ? sd[t - off] : 0;
    __syncthreads();
    sd[t] += tmp;
    __syncthreads();
  }
  int run = sd[t] - sum;  // exclusive base for this thread's R entries
#pragma unroll
  for (int r = 0; r < R; ++r) {
    int tmp = v[r];
    hist[(size_t)(t * R + r) * NB + b] = run;
    run += tmp;
  }
  if (t == BLK - 1) btot[b] = run;
}

// prefix of bucket totals -> ebstart
__global__ void k_scan2(const int* __restrict__ btot, int NB, int* __restrict__ ebstart) {
  __shared__ int s[MAXB];
  for (int j = threadIdx.x; j < NB; j += blockDim.x) s[j] = btot[j];
  __syncthreads();
  if (threadIdx.x == 0) {
    int run = 0;
    for (int j = 0; j < NB; ++j) { ebstart[j] = run; run += s[j]; }
    ebstart[NB] = run;
  }
}

// partition with LDS write-combining + software-pipelined edge prefetch:
// batch i+1's global loads are issued before batch i's copy phase, so HBM/L3
// latency hides under the copy + cursor update. Requires NB <= 128.
__global__ __launch_bounds__(BLK) void k_part_wc(const void* __restrict__ ei,
                                                 const int* __restrict__ flag,
                                                 int E, int chunk, int NB,
                                                 const int* __restrict__ offs,
                                                 const int* __restrict__ ebstart,
                                                 int* __restrict__ packed) {
  __shared__ int gcur[128];
  __shared__ int bcnt[128];
  __shared__ int bbase[128];
  __shared__ int sc[128];
  __shared__ int stage[BATCH];
  __shared__ unsigned char stgb[BATCH];
  const int t = threadIdx.x;
  if (t < NB) gcur[t] = ebstart[t] + offs[(size_t)blockIdx.x * NB + t];
  int is64 = *flag;
  int beg = blockIdx.x * chunk, end = min(E, beg + chunk);
  const int U = BATCH / BLK;  // 8 edges per thread per batch

  int myb[U], myv[U];
  // prologue: load batch 0
  {
    int bend0 = min(end, beg + BATCH);
#pragma unroll
    for (int u = 0; u < U; ++u) {
      int i = beg + u * BLK + t;
      myb[u] = -1;
      if (i < bend0) {
        int s = edge_at(ei, is64, i);
        int d = edge_at(ei, is64, (long long)E + i);
        myb[u] = d >> PSH;
        myv[u] = (s << PSH) | (d & (PART - 1));
      }
    }
  }

  for (int bb = beg; bb < end; bb += BATCH) {
    int bend = min(end, bb + BATCH);
    int len = bend - bb;
    for (int j = t; j < NB; j += BLK) bcnt[j] = 0;
    __syncthreads();
    int myr[U];
#pragma unroll
    for (int u = 0; u < U; ++u)
      if (myb[u] >= 0) myr[u] = atomicAdd(&bcnt[myb[u]], 1);
    __syncthreads();
    // inclusive scan of bcnt over 128 lanes -> sc; exclusive base -> bbase
    if (t < 128) sc[t] = (t < NB) ? bcnt[t] : 0;
    __syncthreads();
    for (int off = 1; off < 128; off <<= 1) {
      int v = (t < 128 && t >= off) ? sc[t - off] : 0;
      __syncthreads();
      if (t < 128) sc[t] += v;
      __syncthreads();
    }
    if (t < NB) bbase[t] = sc[t] - bcnt[t];
    __syncthreads();
    // scatter into bucket-sorted LDS stage
#pragma unroll
    for (int u = 0; u < U; ++u) {
      if (myb[u] >= 0) {
        int p = bbase[myb[u]] + myr[u];
        stage[p] = myv[u];
        stgb[p] = (unsigned char)myb[u];
      }
    }
    // prefetch next batch (overlaps copy + cursor phases)
    int nxb[U], nxv[U];
    int nb_ = bb + BATCH;
    if (nb_ < end) {
      int nbend = min(end, nb_ + BATCH);
#pragma unroll
      for (int u = 0; u < U; ++u) {
        int i = nb_ + u * BLK + t;
        nxb[u] = -1;
        nxv[u] = 0;
        if (i < nbend) {
          int s = edge_at(ei, is64, i);
          int d = edge_at(ei, is64, (long long)E + i);
          nxb[u] = d >> PSH;
          nxv[u] = (s << PSH) | (d & (PART - 1));
        }
      }
    } else {
#pragma unroll
      for (int u = 0; u < U; ++u) { nxb[u] = -1; nxv[u] = 0; }
    }
    __syncthreads();
    // coalesced copy: consecutive j within a bucket -> consecutive global addrs
    for (int j = t; j < len; j += BLK) {
      int b = stgb[j];
      packed[gcur[b] + (j - bbase[b])] = stage[j];
    }
    __syncthreads();
    for (int j = t; j < NB; j += BLK) gcur[j] += bcnt[j];
#pragma unroll
    for (int u = 0; u < U; ++u) { myb[u] = nxb[u]; myv[u] = nxv[u]; }
    __syncthreads();
  }
}

// fallback partition (scattered stores) for NB > 128
__global__ __launch_bounds__(BLK) void k_part(const void* __restrict__ ei,
                                              const int* __restrict__ flag,
                                              int E, int chunk, int NB,
                                              const int* __restrict__ offs,
                                              const int* __restrict__ ebstart,
                                              int* __restrict__ packed) {
  __shared__ int cnt[MAXB];
  int t = threadIdx.x;
  if (t < NB) cnt[t] = ebstart[t] + offs[(size_t)blockIdx.x * NB + t];
  __syncthreads();
  int is64 = *flag;
  int beg = blockIdx.x * chunk, end = min(E, beg + chunk);
  for (int i = beg + t; i < end; i += BLK) {
    int s = edge_at(ei, is64, i);
    int d = edge_at(ei, is64, (long long)E + i);
    int pos = atomicAdd(&cnt[d >> PSH], 1);
    packed[pos] = (s << PSH) | (d & (PART - 1));
  }
}

// slice [lo,hi) of a bucket: head/vector/tail split for aligned int4 loads
#define SLICE_BOUNDS(KB_)                                                     \
  int b = blockIdx.x, k = blockIdx.y;                                         \
  int s0 = ebstart[b], len = ebstart[b + 1] - s0;                             \
  int lo = s0 + (int)((long long)len * k / (KB_));                            \
  int hi = s0 + (int)((long long)len * (k + 1) / (KB_));                      \
  int alo = min((lo + 3) & ~3, hi);                                           \
  int nvec = (hi - alo) & ~3;                                                 \
  int tails = alo + nvec;

// degree count per bucket slice -> int partials [DKB][N]
__global__ __launch_bounds__(BLK) void k_degb(const int* __restrict__ packed,
                                              const int* __restrict__ ebstart,
                                              int N, int* __restrict__ degp) {
  __shared__ int cnt[PART];
  for (int j = threadIdx.x; j < PART; j += BLK) cnt[j] = 0;
  __syncthreads();
  SLICE_BOUNDS(DKB)
  int t = threadIdx.x;
  if (t < alo - lo) atomicAdd(&cnt[packed[lo + t] & (PART - 1)], 1);
  for (int base = alo + t * 4; base < tails; base += BLK * 4) {
    int4 q = *(const int4*)(packed + base);
    atomicAdd(&cnt[q.x & (PART - 1)], 1);
    atomicAdd(&cnt[q.y & (PART - 1)], 1);
    atomicAdd(&cnt[q.z & (PART - 1)], 1);
    atomicAdd(&cnt[q.w & (PART - 1)], 1);
  }
  if (t < hi - tails) atomicAdd(&cnt[packed[tails + t] & (PART - 1)], 1);
  __syncthreads();
  int pstart = b << PSH;
  int psize = min(N - pstart, PART);
  int* out = degp + (size_t)k * N + pstart;
  for (int j = threadIdx.x; j < psize; j += BLK) out[j] = cnt[j];
}

// reduce degree partials -> gx4i = (round(dinv*x*S1), dinv_bits)
__global__ __launch_bounds__(BLK) void k_prepb(const int* __restrict__ degp,
                                               int N, const float* __restrict__ x,
                                               int4* __restrict__ gx4i) {
  int n = blockIdx.x * blockDim.x + threadIdx.x;
  if (n >= N) return;
  int deg = 1;  // self-loop
#pragma unroll
  for (int k = 0; k < DKB; ++k) deg += degp[(size_t)k * N + n];
  float di = rsqrtf((float)deg);
  int4 g;
  g.x = __float2int_rn(di * x[3 * n + 0] * S1SCALE);
  g.y = __float2int_rn(di * x[3 * n + 1] * S1SCALE);
  g.z = __float2int_rn(di * x[3 * n + 2] * S1SCALE);
  g.w = __float_as_int(di);
  gx4i[n] = g;
}

// layer-1 aggregation in LDS (native int atomics) -> int partials [S1KB][3N]
__global__ __launch_bounds__(BLK) void k_s1b(const int* __restrict__ packed,
                                             const int* __restrict__ ebstart,
                                             int N, int S1KB,
                                             const int4* __restrict__ gx4i,
                                             int* __restrict__ p1) {
  __shared__ int acc[3 * PART];  // 24 KB
  for (int j = threadIdx.x; j < 3 * PART; j += BLK) acc[j] = 0;
  __syncthreads();
  SLICE_BOUNDS(S1KB)
  int t = threadIdx.x;
  if (t < alo - lo) {
    int e = packed[lo + t];
    int4 g = gx4i[e >> PSH];
    int a = 3 * (e & (PART - 1));
    atomicAdd(&acc[a + 0], g.x);
    atomicAdd(&acc[a + 1], g.y);
    atomicAdd(&acc[a + 2], g.z);
  }
  for (int base = alo + t * 4; base < tails; base += BLK * 4) {
    int4 q = *(const int4*)(packed + base);
    int4 g0 = gx4i[q.x >> PSH];
    int4 g1 = gx4i[q.y >> PSH];
    int4 g2 = gx4i[q.z >> PSH];
    int4 g3 = gx4i[q.w >> PSH];
    int a0 = 3 * (q.x & (PART - 1)), a1 = 3 * (q.y & (PART - 1));
    int a2 = 3 * (q.z & (PART - 1)), a3 = 3 * (q.w & (PART - 1));
    atomicAdd(&acc[a0 + 0], g0.x);
    atomicAdd(&acc[a0 + 1], g0.y);
    atomicAdd(&acc[a0 + 2], g0.z);
    atomicAdd(&acc[a1 + 0], g1.x);
    atomicAdd(&acc[a1 + 1], g1.y);
    atomicAdd(&acc[a1 + 2], g1.z);
    atomicAdd(&acc[a2 + 0], g2.x);
    atomicAdd(&acc[a2 + 1], g2.y);
    atomicAdd(&acc[a2 + 2], g2.z);
    atomicAdd(&acc[a3 + 0], g3.x);
    atomicAdd(&acc[a3 + 1], g3.y);
    atomicAdd(&acc[a3 + 2], g3.z);
  }
  if (t < hi - tails) {
    int e = packed[tails + t];
    int4 g = gx4i[e >> PSH];
    int a = 3 * (e & (PART - 1));
    atomicAdd(&acc[a + 0], g.x);
    atomicAdd(&acc[a + 1], g.y);
    atomicAdd(&acc[a + 2], g.z);
  }
  __syncthreads();
  int pstart = b << PSH;
  int psize = min(N - pstart, PART);
  int* out = p1 + (size_t)k * 3 * N + 3 * pstart;
  for (int j = threadIdx.x; j < 3 * psize; j += BLK) out[j] = acc[j];
}

// reduce layer-1 int partials + self-loop (exact int sum), fused W1+b1+relu+W2 -> g2i
__global__ __launch_bounds__(BLK) void k_midb(const int* __restrict__ p1, int S1KB,
                                              int N, const int4* __restrict__ gx4i,
                                              const float* __restrict__ W1,
                                              const float* __restrict__ b1,
                                              const float* __restrict__ W2,
                                              int* __restrict__ g2i) {
  int n = blockIdx.x * blockDim.x + threadIdx.x;
  if (n >= N) return;
  int4 g = gx4i[n];
  int A0 = g.x, A1 = g.y, A2 = g.z;  // self-loop (scaled)
  for (int k = 0; k < S1KB; ++k) {
    const int* pp = p1 + (size_t)k * 3 * N + 3 * n;
    A0 += pp[0]; A1 += pp[1]; A2 += pp[2];
  }
  float di = __int_as_float(g.w);
  float sc = di * (1.0f / S1SCALE);
  float a0 = (float)A0 * sc, a1 = (float)A1 * sc, a2 = (float)A2 * sc;
  float h2 = 0.0f;
#pragma unroll
  for (int k = 0; k < 16; ++k) {
    float o = fmaf(a0, W1[k], fmaf(a1, W1[16 + k], fmaf(a2, W1[32 + k], b1[k])));
    o = fmaxf(o, 0.0f);
    h2 = fmaf(o, W2[k], h2);
  }
  g2i[n] = __float2int_rn(di * h2 * S2SCALE);
}

// layer-2 aggregation in LDS (native int atomics) -> int partials [DKB][N]
__global__ __launch_bounds__(BLK) void k_s2b(const int* __restrict__ packed,
                                             const int* __restrict__ ebstart,
                                             int N,
                                             const int* __restrict__ g2i,
                                             int* __restrict__ p2) {
  __shared__ int acc[PART];  // 8 KB
  for (int j = threadIdx.x; j < PART; j += BLK) acc[j] = 0;
  __syncthreads();
  SLICE_BOUNDS(DKB)
  int t = threadIdx.x;
  if (t < alo - lo) {
    int e = packed[lo + t];
    atomicAdd(&acc[e & (PART - 1)], g2i[e >> PSH]);
  }
  for (int base = alo + t * 4; base < tails; base += BLK * 4) {
    int4 q = *(const int4*)(packed + base);
    int v0 = g2i[q.x >> PSH], v1 = g2i[q.y >> PSH];
    int v2 = g2i[q.z >> PSH], v3 = g2i[q.w >> PSH];
    atomicAdd(&acc[q.x & (PART - 1)], v0);
    atomicAdd(&acc[q.y & (PART - 1)], v1);
    atomicAdd(&acc[q.z & (PART - 1)], v2);
    atomicAdd(&acc[q.w & (PART - 1)], v3);
  }
  if (t < hi - tails) {
    int e = packed[tails + t];
    atomicAdd(&acc[e & (PART - 1)], g2i[e >> PSH]);
  }
  __syncthreads();
  int pstart = b << PSH;
  int psize = min(N - pstart, PART);
  int* out = p2 + (size_t)k * N + pstart;
  for (int j = threadIdx.x; j < psize; j += BLK) out[j] = acc[j];
}

// reduce layer-2 int partials + self-loop + bias -> out
__global__ __launch_bounds__(BLK) void k_finalb(const int* __restrict__ p2,
                                                int N, const int* __restrict__ g2i,
                                                const int4* __restrict__ gx4i,
                                                const float* __restrict__ b2,
                                                float* __restrict__ out) {
  int n = blockIdx.x * blockDim.x + threadIdx.x;
  if (n >= N) return;
  int S = g2i[n];  // self-loop (scaled)
#pragma unroll
  for (int k = 0; k < DKB; ++k) S += p2[(size_t)k * N + n];
  float di = __int_as_float(gx4i[n].w);
  out[n] = di * ((float)S * (1.0f / S2SCALE)) + b2[0];
}

// ---------------- fallback (round-1 atomic) path ----------------

__global__ void k_zero(float* __restrict__ p, int n) {
  int i = blockIdx.x * blockDim.x + threadIdx.x;
  if (i < n) p[i] = 0.0f;
}

__global__ void k_deg(const void* __restrict__ idx, const int* __restrict__ flag,
                      int E, int* __restrict__ deg) {
  int i = blockIdx.x * blockDim.x + threadIdx.x;
  if (i >= E) return;
  int is64 = *flag;
  atomicAdd(&deg[edge_at(idx, is64, (long long)E + i)], 1);
}

__global__ void k_prep(const float* __restrict__ x, const int* __restrict__ deg,
                       float* __restrict__ dinv, float* __restrict__ gx, int N) {
  int n = blockIdx.x * blockDim.x + threadIdx.x;
  if (n >= N) return;
  float di = rsqrtf((float)(deg[n] + 1));
  dinv[n] = di;
  gx[3 * n + 0] = di * x[3 * n + 0];
  gx[3 * n + 1] = di * x[3 * n + 1];
  gx[3 * n + 2] = di * x[3 * n + 2];
}

__global__ void k_scat1(const void* __restrict__ idx, const int* __restrict__ flag,
                        int E, const float* __restrict__ gx, float* __restrict__ aggx) {
  int i = blockIdx.x * blockDim.x + threadIdx.x;
  if (i >= E) return;
  int is64 = *flag;
  int s = edge_at(idx, is64, i);
  int d = edge_at(idx, is64, (long long)E + i);
  unsafeAtomicAdd(&aggx[3 * d + 0], gx[3 * s + 0]);
  unsafeAtomicAdd(&aggx[3 * d + 1], gx[3 * s + 1]);
  unsafeAtomicAdd(&aggx[3 * d + 2], gx[3 * s + 2]);
}

__global__ void k_mid(const float* __restrict__ aggx, const float* __restrict__ gx,
                      const float* __restrict__ dinv,
                      const float* __restrict__ W1, const float* __restrict__ b1,
                      const float* __restrict__ W2, float* __restrict__ g2, int N) {
  int n = blockIdx.x * blockDim.x + threadIdx.x;
  if (n >= N) return;
  float di = dinv[n];
  float a0 = (aggx[3 * n + 0] + gx[3 * n + 0]) * di;
  float a1 = (aggx[3 * n + 1] + gx[3 * n + 1]) * di;
  float a2 = (aggx[3 * n + 2] + gx[3 * n + 2]) * di;
  float h2 = 0.0f;
#pragma unroll
  for (int k = 0; k < 16; ++k) {
    float o = fmaf(a0, W1[k], fmaf(a1, W1[16 + k], fmaf(a2, W1[32 + k], b1[k])));
    o = fmaxf(o, 0.0f);
    h2 = fmaf(o, W2[k], h2);
  }
  g2[n] = di * h2;
}

__global__ void k_scat2(const void* __restrict__ idx, const int* __restrict__ flag,
                        int E, const float* __restrict__ g2, float* __restrict__ agg2) {
  int i = blockIdx.x * blockDim.x + threadIdx.x;
  if (i >= E) return;
  int is64 = *flag;
  int s = edge_at(idx, is64, i);
  int d = edge_at(idx, is64, (long long)E + i);
  unsafeAtomicAdd(&agg2[d], g2[s]);
}

__global__ void k_final(const float* __restrict__ agg2, const float* __restrict__ g2,
                        const float* __restrict__ dinv, const float* __restrict__ b2,
                        float* __restrict__ out, int N) {
  int n = blockIdx.x * blockDim.x + threadIdx.x;
  if (n >= N) return;
  out[n] = dinv[n] * (agg2[n] + g2[n]) + b2[0];
}

// ---------------- launch ----------------

extern "C" void kernel_launch(void* const* d_in, const int* in_sizes, int n_in,
                              void* d_out, int out_size, void* d_ws, size_t ws_size,
                              hipStream_t stream) {
  const float* x  = (const float*)d_in[0];
  const void*  ei = d_in[1];
  const float* W1 = (const float*)d_in[2];
  const float* b1 = (const float*)d_in[3];
  const float* W2 = (const float*)d_in[4];
  const float* b2 = (const float*)d_in[5];
  float* out = (float*)d_out;

  const int N = in_sizes[0] / 3;   // 200000
  const int E = in_sizes[1] / 2;   // 6400000
  const int NB = (N + PART - 1) >> PSH;  // 98

  char* ws = (char*)d_ws;
  int gN = (N + BLK - 1) / BLK;
  int gE = (E + BLK - 1) / BLK;

  // ws layout (256B-aligned cursor)
  size_t cur = 0;
  auto take = [&](size_t bytes) { size_t o = cur; cur += (bytes + 255) & ~(size_t)255; return (void*)(ws + o); };
  int*   flag    = (int*)take(256);
  int*   ebstart = (int*)take((size_t)(MAXB + 1) * 4);
  int*   btot    = (int*)take((size_t)MAXB * 4);
  int*   hist    = (int*)take((size_t)GHB * NB * 4);   // [block][bucket], scanned in place
  int*   packed  = (int*)take((size_t)E * 4);
  int4*  gx4i    = (int4*)take((size_t)N * 16);
  int*   g2i     = (int*)take((size_t)N * 4);
  size_t fixed = cur;

  // choose S1KB so partial region fits: partial = S1KB * 3N ints (>= DKB*N needed)
  int s1kb = 12;
  while (s1kb > 6 && fixed + (size_t)s1kb * 3 * N * 4 > ws_size) s1kb -= 2;

  if (fixed + (size_t)s1kb * 3 * N * 4 <= ws_size && NB <= MAXB) {
    int* partial = (int*)take((size_t)s1kb * 3 * N * 4);
    int chunk = (((E + GHB - 1) / GHB) + 3) & ~3;

    k_detect<<<1, 256, 0, stream>>>((const unsigned*)ei, flag);
    k_hist<<<GHB, BLK, 0, stream>>>(ei, flag, E, chunk, NB, hist);
    k_scan1<<<NB, BLK, 0, stream>>>(hist, NB, btot);
    k_scan2<<<1, 256, 0, stream>>>(btot, NB, ebstart);
    if (NB <= 128)
      k_part_wc<<<GHB, BLK, 0, stream>>>(ei, flag, E, chunk, NB, hist, ebstart, packed);
    else
      k_part<<<GHB, BLK, 0, stream>>>(ei, flag, E, chunk, NB, hist, ebstart, packed);
    k_degb<<<dim3(NB, DKB), BLK, 0, stream>>>(packed, ebstart, N, partial);
    k_prepb<<<gN, BLK, 0, stream>>>((const int*)partial, N, x, gx4i);
    k_s1b<<<dim3(NB, s1kb), BLK, 0, stream>>>(packed, ebstart, N, s1kb, (const int4*)gx4i, partial);
    k_midb<<<gN, BLK, 0, stream>>>(partial, s1kb, N, (const int4*)gx4i, W1, b1, W2, g2i);
    k_s2b<<<dim3(NB, DKB), BLK, 0, stream>>>(packed, ebstart, N, (const int*)g2i, partial);
    k_finalb<<<gN, BLK, 0, stream>>>(partial, N, (const int*)g2i, (const int4*)gx4i, b2, out);
  } else {
    // round-1 fallback
    int*   deg   = (int*)(ws + 256);
    float* aggx  = (float*)(ws + 256 + 4ll * N);
    float* agg2b = (float*)(ws + 256 + 4ll * N * 4);
    float* dinvf = (float*)(ws + 256 + 4ll * N * 5);
    float* gx    = (float*)(ws + 256 + 4ll * N * 6);
    float* g2f   = (float*)(ws + 256 + 4ll * N * 9);

    int gZ = (5 * N + BLK - 1) / BLK;

    k_detect<<<1, 256, 0, stream>>>((const unsigned*)ei, (int*)ws);
    k_zero<<<gZ, BLK, 0, stream>>>((float*)deg, 5 * N);
    k_deg<<<gE, BLK, 0, stream>>>(ei, (int*)ws, E, deg);
    k_prep<<<gN, BLK, 0, stream>>>(x, deg, dinvf, gx, N);
    k_scat1<<<gE, BLK, 0, stream>>>(ei, (int*)ws, E, gx, aggx);
    k_mid<<<gN, BLK, 0, stream>>>(aggx, gx, dinvf, W1, b1, W2, g2f, N);
    k_scat2<<<gE, BLK, 0, stream>>>(ei, (int*)ws, E, g2f, agg2b);
    k_final<<<gN, BLK, 0, stream>>>(agg2b, g2f, dinvf, b2, out, N);
  }
}

// Round 21
// 137.416 us; speedup vs baseline: 1.1132x; 1.0143x over previous
//
#include <hip/hip_runtime.h>

#define BLK 256
#define BLKA 512           // wide blocks for bucket-consumer kernels
#define PSH 11
#define PART 2048          // nodes per dst-bucket
#define GHB 2048           // blocks in hist/partition passes
#define MAXB 256           // max buckets supported by LDS counters
#define BATCH 2048         // edges per write-combining batch in k_part_wc
#define DKB 16             // degree / layer-2 slices per bucket
#define S1SCALE 2097152.0f // 2^21 fixed-point scale for layer-1 messages
#define S2SCALE 524288.0f  // 2^19 fixed-point scale for layer-2 messages

// ---------------- helpers ----------------

__device__ __forceinline__ int edge_at(const void* idx, int is64, long long pos) {
  return is64 ? (int)((const long long*)idx)[pos] : ((const int*)idx)[pos];
}

// Detect int64 vs int32 storage: for int64 values < 2^31 the odd 32-bit words are 0.
__global__ void k_detect(const unsigned* __restrict__ w, int* __restrict__ flag) {
  __shared__ int any;
  if (threadIdx.x == 0) any = 0;
  __syncthreads();
  if (w[2 * threadIdx.x + 1] != 0u) atomicOr(&any, 1);
  __syncthreads();
  if (threadIdx.x == 0) *flag = (any == 0) ? 1 : 0;  // 1 => int64
}

// ---------------- bucketed (counting-sort) path ----------------

// per-block histogram of dst buckets; hist layout [block][bucket] (coalesced)
__global__ __launch_bounds__(BLK) void k_hist(const void* __restrict__ ei,
                                              const int* __restrict__ flag,
                                              int E, int chunk, int NB,
                                              int* __restrict__ hist) {
  __shared__ int cnt[MAXB];
  for (int j = threadIdx.x; j < NB; j += BLK) cnt[j] = 0;
  __syncthreads();
  int is64 = *flag;
  int beg = blockIdx.x * chunk, end = min(E, beg + chunk);
  int i = beg + (int)threadIdx.x;
  for (; i + 3 * BLK < end; i += 4 * BLK) {
    int d0 = edge_at(ei, is64, (long long)E + i);
    int d1 = edge_at(ei, is64, (long long)E + i + BLK);
    int d2 = edge_at(ei, is64, (long long)E + i + 2 * BLK);
    int d3 = edge_at(ei, is64, (long long)E + i + 3 * BLK);
    atomicAdd(&cnt[d0 >> PSH], 1);
    atomicAdd(&cnt[d1 >> PSH], 1);
    atomicAdd(&cnt[d2 >> PSH], 1);
    atomicAdd(&cnt[d3 >> PSH], 1);
  }
  for (; i < end; i += BLK)
    atomicAdd(&cnt[edge_at(ei, is64, (long long)E + i) >> PSH], 1);
  __syncthreads();
  int* row = hist + (size_t)blockIdx.x * NB;
  for (int j = threadIdx.x; j < NB; j += BLK) row[j] = cnt[j];
}

// per-bucket parallel scan over the GHB chunk counts; exclusive in place.
__global__ __launch_bounds__(BLK) void k_scan1(int* __restrict__ hist, int NB,
                                               int* __restrict__ btot) {
  const int R = GHB / BLK;
  __shared__ int sd[BLK];
  int b = blockIdx.x, t = threadIdx.x;
  int v[R];
  int sum = 0;
#pragma unroll
  for (int r = 0; r < R; ++r) {
    v[r] = hist[(size_t)(t * R + r) * NB + b];
    sum += v[r];
  }
  sd[t] = sum;
  __syncthreads();
  for (int off = 1; off < BLK; off <<= 1) {
    int tmp = (t >= off) ? sd[t - off] : 0;
    __syncthreads();
    sd[t] += tmp;
    __syncthreads();
  }
  int run = sd[t] - sum;  // exclusive base for this thread's R entries
#pragma unroll
  for (int r = 0; r < R; ++r) {
    int tmp = v[r];
    hist[(size_t)(t * R + r) * NB + b] = run;
    run += tmp;
  }
  if (t == BLK - 1) btot[b] = run;
}

// prefix of bucket totals -> ebstart
__global__ void k_scan2(const int* __restrict__ btot, int NB, int* __restrict__ ebstart) {
  __shared__ int s[MAXB];
  for (int j = threadIdx.x; j < NB; j += blockDim.x) s[j] = btot[j];
  __syncthreads();
  if (threadIdx.x == 0) {
    int run = 0;
    for (int j = 0; j < NB; ++j) { ebstart[j] = run; run += s[j]; }
    ebstart[NB] = run;
  }
}

// partition with LDS write-combining + software-pipelined edge prefetch.
__global__ __launch_bounds__(BLK) void k_part_wc(const void* __restrict__ ei,
                                                 const int* __restrict__ flag,
                                                 int E, int chunk, int NB,
                                                 const int* __restrict__ offs,
                                                 const int* __restrict__ ebstart,
                                                 int* __restrict__ packed) {
  __shared__ int gcur[128];
  __shared__ int bcnt[128];
  __shared__ int bbase[128];
  __shared__ int sc[128];
  __shared__ int stage[BATCH];
  __shared__ unsigned char stgb[BATCH];
  const int t = threadIdx.x;
  if (t < NB) gcur[t] = ebstart[t] + offs[(size_t)blockIdx.x * NB + t];
  int is64 = *flag;
  int beg = blockIdx.x * chunk, end = min(E, beg + chunk);
  const int U = BATCH / BLK;  // 8 edges per thread per batch

  int myb[U], myv[U];
  // prologue: load batch 0
  {
    int bend0 = min(end, beg + BATCH);
#pragma unroll
    for (int u = 0; u < U; ++u) {
      int i = beg + u * BLK + t;
      myb[u] = -1;
      if (i < bend0) {
        int s = edge_at(ei, is64, i);
        int d = edge_at(ei, is64, (long long)E + i);
        myb[u] = d >> PSH;
        myv[u] = (s << PSH) | (d & (PART - 1));
      }
    }
  }

  for (int bb = beg; bb < end; bb += BATCH) {
    int bend = min(end, bb + BATCH);
    int len = bend - bb;
    for (int j = t; j < NB; j += BLK) bcnt[j] = 0;
    __syncthreads();
    int myr[U];
#pragma unroll
    for (int u = 0; u < U; ++u)
      if (myb[u] >= 0) myr[u] = atomicAdd(&bcnt[myb[u]], 1);
    __syncthreads();
    // inclusive scan of bcnt over 128 lanes -> sc; exclusive base -> bbase
    if (t < 128) sc[t] = (t < NB) ? bcnt[t] : 0;
    __syncthreads();
    for (int off = 1; off < 128; off <<= 1) {
      int v = (t < 128 && t >= off) ? sc[t - off] : 0;
      __syncthreads();
      if (t < 128) sc[t] += v;
      __syncthreads();
    }
    if (t < NB) bbase[t] = sc[t] - bcnt[t];
    __syncthreads();
    // scatter into bucket-sorted LDS stage
#pragma unroll
    for (int u = 0; u < U; ++u) {
      if (myb[u] >= 0) {
        int p = bbase[myb[u]] + myr[u];
        stage[p] = myv[u];
        stgb[p] = (unsigned char)myb[u];
      }
    }
    // prefetch next batch (overlaps copy + cursor phases)
    int nxb[U], nxv[U];
    int nb_ = bb + BATCH;
    if (nb_ < end) {
      int nbend = min(end, nb_ + BATCH);
#pragma unroll
      for (int u = 0; u < U; ++u) {
        int i = nb_ + u * BLK + t;
        nxb[u] = -1;
        nxv[u] = 0;
        if (i < nbend) {
          int s = edge_at(ei, is64, i);
          int d = edge_at(ei, is64, (long long)E + i);
          nxb[u] = d >> PSH;
          nxv[u] = (s << PSH) | (d & (PART - 1));
        }
      }
    } else {
#pragma unroll
      for (int u = 0; u < U; ++u) { nxb[u] = -1; nxv[u] = 0; }
    }
    __syncthreads();
    // coalesced copy: consecutive j within a bucket -> consecutive global addrs
    for (int j = t; j < len; j += BLK) {
      int b = stgb[j];
      packed[gcur[b] + (j - bbase[b])] = stage[j];
    }
    __syncthreads();
    for (int j = t; j < NB; j += BLK) gcur[j] += bcnt[j];
#pragma unroll
    for (int u = 0; u < U; ++u) { myb[u] = nxb[u]; myv[u] = nxv[u]; }
    __syncthreads();
  }
}

// fallback partition (scattered stores) for NB > 128
__global__ __launch_bounds__(BLK) void k_part(const void* __restrict__ ei,
                                              const int* __restrict__ flag,
                                              int E, int chunk, int NB,
                                              const int* __restrict__ offs,
                                              const int* __restrict__ ebstart,
                                              int* __restrict__ packed) {
  __shared__ int cnt[MAXB];
  int t = threadIdx.x;
  if (t < NB) cnt[t] = ebstart[t] + offs[(size_t)blockIdx.x * NB + t];
  __syncthreads();
  int is64 = *flag;
  int beg = blockIdx.x * chunk, end = min(E, beg + chunk);
  for (int i = beg + t; i < end; i += BLK) {
    int s = edge_at(ei, is64, i);
    int d = edge_at(ei, is64, (long long)E + i);
    int pos = atomicAdd(&cnt[d >> PSH], 1);
    packed[pos] = (s << PSH) | (d & (PART - 1));
  }
}

// slice [lo,hi) of a bucket: head/vector/tail split for aligned int4 loads
#define SLICE_BOUNDS(KB_, TW_)                                                \
  int b = blockIdx.x, k = blockIdx.y;                                         \
  int s0 = ebstart[b], len = ebstart[b + 1] - s0;                             \
  int lo = s0 + (int)((long long)len * k / (KB_));                            \
  int hi = s0 + (int)((long long)len * (k + 1) / (KB_));                      \
  int alo = min((lo + 3) & ~3, hi);                                           \
  int nvec = (hi - alo) & ~3;                                                 \
  int tails = alo + nvec;

// degree count per bucket slice -> int partials [DKB][N]  (512 threads)
__global__ __launch_bounds__(BLKA) void k_degb(const int* __restrict__ packed,
                                               const int* __restrict__ ebstart,
                                               int N, int* __restrict__ degp) {
  __shared__ int cnt[PART];
  for (int j = threadIdx.x; j < PART; j += BLKA) cnt[j] = 0;
  __syncthreads();
  SLICE_BOUNDS(DKB, BLKA)
  int t = threadIdx.x;
  if (t < alo - lo) atomicAdd(&cnt[packed[lo + t] & (PART - 1)], 1);
  for (int base = alo + t * 4; base < tails; base += BLKA * 4) {
    int4 q = *(const int4*)(packed + base);
    atomicAdd(&cnt[q.x & (PART - 1)], 1);
    atomicAdd(&cnt[q.y & (PART - 1)], 1);
    atomicAdd(&cnt[q.z & (PART - 1)], 1);
    atomicAdd(&cnt[q.w & (PART - 1)], 1);
  }
  if (t < hi - tails) atomicAdd(&cnt[packed[tails + t] & (PART - 1)], 1);
  __syncthreads();
  int pstart = b << PSH;
  int psize = min(N - pstart, PART);
  int* out = degp + (size_t)k * N + pstart;
  for (int j = threadIdx.x; j < psize; j += BLKA) out[j] = cnt[j];
}

// reduce degree partials -> gx4i = (round(dinv*x*S1), dinv_bits)
__global__ __launch_bounds__(BLK) void k_prepb(const int* __restrict__ degp,
                                               int N, const float* __restrict__ x,
                                               int4* __restrict__ gx4i) {
  int n = blockIdx.x * blockDim.x + threadIdx.x;
  if (n >= N) return;
  int deg = 1;  // self-loop
#pragma unroll
  for (int k = 0; k < DKB; ++k) deg += degp[(size_t)k * N + n];
  float di = rsqrtf((float)deg);
  int4 g;
  g.x = __float2int_rn(di * x[3 * n + 0] * S1SCALE);
  g.y = __float2int_rn(di * x[3 * n + 1] * S1SCALE);
  g.z = __float2int_rn(di * x[3 * n + 2] * S1SCALE);
  g.w = __float_as_int(di);
  gx4i[n] = g;
}

// layer-1 aggregation in LDS (native int atomics) -> int partials [S1KB][3N]  (512 threads)
__global__ __launch_bounds__(BLKA) void k_s1b(const int* __restrict__ packed,
                                              const int* __restrict__ ebstart,
                                              int N, int S1KB,
                                              const int4* __restrict__ gx4i,
                                              int* __restrict__ p1) {
  __shared__ int acc[3 * PART];  // 24 KB
  for (int j = threadIdx.x; j < 3 * PART; j += BLKA) acc[j] = 0;
  __syncthreads();
  SLICE_BOUNDS(S1KB, BLKA)
  int t = threadIdx.x;
  if (t < alo - lo) {
    int e = packed[lo + t];
    int4 g = gx4i[e >> PSH];
    int a = 3 * (e & (PART - 1));
    atomicAdd(&acc[a + 0], g.x);
    atomicAdd(&acc[a + 1], g.y);
    atomicAdd(&acc[a + 2], g.z);
  }
  for (int base = alo + t * 4; base < tails; base += BLKA * 4) {
    int4 q = *(const int4*)(packed + base);
    int4 g0 = gx4i[q.x >> PSH];
    int4 g1 = gx4i[q.y >> PSH];
    int4 g2 = gx4i[q.z >> PSH];
    int4 g3 = gx4i[q.w >> PSH];
    int a0 = 3 * (q.x & (PART - 1)), a1 = 3 * (q.y & (PART - 1));
    int a2 = 3 * (q.z & (PART - 1)), a3 = 3 * (q.w & (PART - 1));
    atomicAdd(&acc[a0 + 0], g0.x);
    atomicAdd(&acc[a0 + 1], g0.y);
    atomicAdd(&acc[a0 + 2], g0.z);
    atomicAdd(&acc[a1 + 0], g1.x);
    atomicAdd(&acc[a1 + 1], g1.y);
    atomicAdd(&acc[a1 + 2], g1.z);
    atomicAdd(&acc[a2 + 0], g2.x);
    atomicAdd(&acc[a2 + 1], g2.y);
    atomicAdd(&acc[a2 + 2], g2.z);
    atomicAdd(&acc[a3 + 0], g3.x);
    atomicAdd(&acc[a3 + 1], g3.y);
    atomicAdd(&acc[a3 + 2], g3.z);
  }
  if (t < hi - tails) {
    int e = packed[tails + t];
    int4 g = gx4i[e >> PSH];
    int a = 3 * (e & (PART - 1));
    atomicAdd(&acc[a + 0], g.x);
    atomicAdd(&acc[a + 1], g.y);
    atomicAdd(&acc[a + 2], g.z);
  }
  __syncthreads();
  int pstart = b << PSH;
  int psize = min(N - pstart, PART);
  int* out = p1 + (size_t)k * 3 * N + 3 * pstart;
  for (int j = threadIdx.x; j < 3 * psize; j += BLKA) out[j] = acc[j];
}

// reduce layer-1 int partials + self-loop (exact int sum), fused W1+b1+relu+W2 -> g2i
__global__ __launch_bounds__(BLK) void k_midb(const int* __restrict__ p1, int S1KB,
                                              int N, const int4* __restrict__ gx4i,
                                              const float* __restrict__ W1,
                                              const float* __restrict__ b1,
                                              const float* __restrict__ W2,
                                              int* __restrict__ g2i) {
  int n = blockIdx.x * blockDim.x + threadIdx.x;
  if (n >= N) return;
  int4 g = gx4i[n];
  int A0 = g.x, A1 = g.y, A2 = g.z;  // self-loop (scaled)
  for (int k = 0; k < S1KB; ++k) {
    const int* pp = p1 + (size_t)k * 3 * N + 3 * n;
    A0 += pp[0]; A1 += pp[1]; A2 += pp[2];
  }
  float di = __int_as_float(g.w);
  float sc = di * (1.0f / S1SCALE);
  float a0 = (float)A0 * sc, a1 = (float)A1 * sc, a2 = (float)A2 * sc;
  float h2 = 0.0f;
#pragma unroll
  for (int k = 0; k < 16; ++k) {
    float o = fmaf(a0, W1[k], fmaf(a1, W1[16 + k], fmaf(a2, W1[32 + k], b1[k])));
    o = fmaxf(o, 0.0f);
    h2 = fmaf(o, W2[k], h2);
  }
  g2i[n] = __float2int_rn(di * h2 * S2SCALE);
}

// layer-2 aggregation in LDS (native int atomics) -> int partials [DKB][N]  (512 threads)
__global__ __launch_bounds__(BLKA) void k_s2b(const int* __restrict__ packed,
                                              const int* __restrict__ ebstart,
                                              int N,
                                              const int* __restrict__ g2i,
                                              int* __restrict__ p2) {
  __shared__ int acc[PART];  // 8 KB
  for (int j = threadIdx.x; j < PART; j += BLKA) acc[j] = 0;
  __syncthreads();
  SLICE_BOUNDS(DKB, BLKA)
  int t = threadIdx.x;
  if (t < alo - lo) {
    int e = packed[lo + t];
    atomicAdd(&acc[e & (PART - 1)], g2i[e >> PSH]);
  }
  for (int base = alo + t * 4; base < tails; base += BLKA * 4) {
    int4 q = *(const int4*)(packed + base);
    int v0 = g2i[q.x >> PSH], v1 = g2i[q.y >> PSH];
    int v2 = g2i[q.z >> PSH], v3 = g2i[q.w >> PSH];
    atomicAdd(&acc[q.x & (PART - 1)], v0);
    atomicAdd(&acc[q.y & (PART - 1)], v1);
    atomicAdd(&acc[q.z & (PART - 1)], v2);
    atomicAdd(&acc[q.w & (PART - 1)], v3);
  }
  if (t < hi - tails) {
    int e = packed[tails + t];
    atomicAdd(&acc[e & (PART - 1)], g2i[e >> PSH]);
  }
  __syncthreads();
  int pstart = b << PSH;
  int psize = min(N - pstart, PART);
  int* out = p2 + (size_t)k * N + pstart;
  for (int j = threadIdx.x; j < psize; j += BLKA) out[j] = acc[j];
}

// reduce layer-2 int partials + self-loop + bias -> out
__global__ __launch_bounds__(BLK) void k_finalb(const int* __restrict__ p2,
                                                int N, const int* __restrict__ g2i,
                                                const int4* __restrict__ gx4i,
                                                const float* __restrict__ b2,
                                                float* __restrict__ out) {
  int n = blockIdx.x * blockDim.x + threadIdx.x;
  if (n >= N) return;
  int S = g2i[n];  // self-loop (scaled)
#pragma unroll
  for (int k = 0; k < DKB; ++k) S += p2[(size_t)k * N + n];
  float di = __int_as_float(gx4i[n].w);
  out[n] = di * ((float)S * (1.0f / S2SCALE)) + b2[0];
}

// ---------------- fallback (round-1 atomic) path ----------------

__global__ void k_zero(float* __restrict__ p, int n) {
  int i = blockIdx.x * blockDim.x + threadIdx.x;
  if (i < n) p[i] = 0.0f;
}

__global__ void k_deg(const void* __restrict__ idx, const int* __restrict__ flag,
                      int E, int* __restrict__ deg) {
  int i = blockIdx.x * blockDim.x + threadIdx.x;
  if (i >= E) return;
  int is64 = *flag;
  atomicAdd(&deg[edge_at(idx, is64, (long long)E + i)], 1);
}

__global__ void k_prep(const float* __restrict__ x, const int* __restrict__ deg,
                       float* __restrict__ dinv, float* __restrict__ gx, int N) {
  int n = blockIdx.x * blockDim.x + threadIdx.x;
  if (n >= N) return;
  float di = rsqrtf((float)(deg[n] + 1));
  dinv[n] = di;
  gx[3 * n + 0] = di * x[3 * n + 0];
  gx[3 * n + 1] = di * x[3 * n + 1];
  gx[3 * n + 2] = di * x[3 * n + 2];
}

__global__ void k_scat1(const void* __restrict__ idx, const int* __restrict__ flag,
                        int E, const float* __restrict__ gx, float* __restrict__ aggx) {
  int i = blockIdx.x * blockDim.x + threadIdx.x;
  if (i >= E) return;
  int is64 = *flag;
  int s = edge_at(idx, is64, i);
  int d = edge_at(idx, is64, (long long)E + i);
  unsafeAtomicAdd(&aggx[3 * d + 0], gx[3 * s + 0]);
  unsafeAtomicAdd(&aggx[3 * d + 1], gx[3 * s + 1]);
  unsafeAtomicAdd(&aggx[3 * d + 2], gx[3 * s + 2]);
}

__global__ void k_mid(const float* __restrict__ aggx, const float* __restrict__ gx,
                      const float* __restrict__ dinv,
                      const float* __restrict__ W1, const float* __restrict__ b1,
                      const float* __restrict__ W2, float* __restrict__ g2, int N) {
  int n = blockIdx.x * blockDim.x + threadIdx.x;
  if (n >= N) return;
  float di = dinv[n];
  float a0 = (aggx[3 * n + 0] + gx[3 * n + 0]) * di;
  float a1 = (aggx[3 * n + 1] + gx[3 * n + 1]) * di;
  float a2 = (aggx[3 * n + 2] + gx[3 * n + 2]) * di;
  float h2 = 0.0f;
#pragma unroll
  for (int k = 0; k < 16; ++k) {
    float o = fmaf(a0, W1[k], fmaf(a1, W1[16 + k], fmaf(a2, W1[32 + k], b1[k])));
    o = fmaxf(o, 0.0f);
    h2 = fmaf(o, W2[k], h2);
  }
  g2[n] = di * h2;
}

__global__ void k_scat2(const void* __restrict__ idx, const int* __restrict__ flag,
                        int E, const float* __restrict__ g2, float* __restrict__ agg2) {
  int i = blockIdx.x * blockDim.x + threadIdx.x;
  if (i >= E) return;
  int is64 = *flag;
  int s = edge_at(idx, is64, i);
  int d = edge_at(idx, is64, (long long)E + i);
  unsafeAtomicAdd(&agg2[d], g2[s]);
}

__global__ void k_final(const float* __restrict__ agg2, const float* __restrict__ g2,
                        const float* __restrict__ dinv, const float* __restrict__ b2,
                        float* __restrict__ out, int N) {
  int n = blockIdx.x * blockDim.x + threadIdx.x;
  if (n >= N) return;
  out[n] = dinv[n] * (agg2[n] + g2[n]) + b2[0];
}

// ---------------- launch ----------------

extern "C" void kernel_launch(void* const* d_in, const int* in_sizes, int n_in,
                              void* d_out, int out_size, void* d_ws, size_t ws_size,
                              hipStream_t stream) {
  const float* x  = (const float*)d_in[0];
  const void*  ei = d_in[1];
  const float* W1 = (const float*)d_in[2];
  const float* b1 = (const float*)d_in[3];
  const float* W2 = (const float*)d_in[4];
  const float* b2 = (const float*)d_in[5];
  float* out = (float*)d_out;

  const int N = in_sizes[0] / 3;   // 200000
  const int E = in_sizes[1] / 2;   // 6400000
  const int NB = (N + PART - 1) >> PSH;  // 98

  char* ws = (char*)d_ws;
  int gN = (N + BLK - 1) / BLK;
  int gE = (E + BLK - 1) / BLK;

  // ws layout (256B-aligned cursor)
  size_t cur = 0;
  auto take = [&](size_t bytes) { size_t o = cur; cur += (bytes + 255) & ~(size_t)255; return (void*)(ws + o); };
  int*   flag    = (int*)take(256);
  int*   ebstart = (int*)take((size_t)(MAXB + 1) * 4);
  int*   btot    = (int*)take((size_t)MAXB * 4);
  int*   hist    = (int*)take((size_t)GHB * NB * 4);   // [block][bucket], scanned in place
  int*   packed  = (int*)take((size_t)E * 4);
  int4*  gx4i    = (int4*)take((size_t)N * 16);
  int*   g2i     = (int*)take((size_t)N * 4);
  size_t fixed = cur;

  // choose S1KB so partial region fits: partial = S1KB * 3N ints (>= DKB*N needed)
  int s1kb = 12;
  while (s1kb > 6 && fixed + (size_t)s1kb * 3 * N * 4 > ws_size) s1kb -= 2;

  if (fixed + (size_t)s1kb * 3 * N * 4 <= ws_size && NB <= 128) {
    int* partial = (int*)take((size_t)s1kb * 3 * N * 4);
    int chunk = (((E + GHB - 1) / GHB) + 3) & ~3;

    k_detect<<<1, 256, 0, stream>>>((const unsigned*)ei, flag);
    k_hist<<<GHB, BLK, 0, stream>>>(ei, flag, E, chunk, NB, hist);
    k_scan1<<<NB, BLK, 0, stream>>>(hist, NB, btot);
    k_scan2<<<1, 256, 0, stream>>>(btot, NB, ebstart);
    k_part_wc<<<GHB, BLK, 0, stream>>>(ei, flag, E, chunk, NB, hist, ebstart, packed);
    k_degb<<<dim3(NB, DKB), BLKA, 0, stream>>>(packed, ebstart, N, partial);
    k_prepb<<<gN, BLK, 0, stream>>>((const int*)partial, N, x, gx4i);
    k_s1b<<<dim3(NB, s1kb), BLKA, 0, stream>>>(packed, ebstart, N, s1kb, (const int4*)gx4i, partial);
    k_midb<<<gN, BLK, 0, stream>>>(partial, s1kb, N, (const int4*)gx4i, W1, b1, W2, g2i);
    k_s2b<<<dim3(NB, DKB), BLKA, 0, stream>>>(packed, ebstart, N, (const int*)g2i, partial);
    k_finalb<<<gN, BLK, 0, stream>>>(partial, N, (const int*)g2i, (const int4*)gx4i, b2, out);
  } else {
    // round-1 fallback
    int*   deg   = (int*)(ws + 256);
    float* aggx  = (float*)(ws + 256 + 4ll * N);
    float* agg2b = (float*)(ws + 256 + 4ll * N * 4);
    float* dinvf = (float*)(ws + 256 + 4ll * N * 5);
    float* gx    = (float*)(ws + 256 + 4ll * N * 6);
    float* g2f   = (float*)(ws + 256 + 4ll * N * 9);

    int gZ = (5 * N + BLK - 1) / BLK;

    k_detect<<<1, 256, 0, stream>>>((const unsigned*)ei, (int*)ws);
    k_zero<<<gZ, BLK, 0, stream>>>((float*)deg, 5 * N);
    k_deg<<<gE, BLK, 0, stream>>>(ei, (int*)ws, E, deg);
    k_prep<<<gN, BLK, 0, stream>>>(x, deg, dinvf, gx, N);
    k_scat1<<<gE, BLK, 0, stream>>>(ei, (int*)ws, E, gx, aggx);
    k_mid<<<gN, BLK, 0, stream>>>(aggx, gx, dinvf, W1, b1, W2, g2f, N);
    k_scat2<<<gE, BLK, 0, stream>>>(ei, (int*)ws, E, g2f, agg2b);
    k_final<<<gN, BLK, 0, stream>>>(agg2b, g2f, dinvf, b2, out, N);
  }
}